// Round 2
// 660.712 us; speedup vs baseline: 1.0382x; 1.0382x over previous
//
#include <hip/hip_runtime.h>
#include <hip/hip_fp16.h>

// VGAE: h = relu(GC(x,W1)); agg2 = norm-agg(h); mean=agg2@W2+b2; ls=agg2@W3+b3;
// z = mean + noise*exp(ls); out = sigmoid(z @ z^T)
// GC(x,W) = (segsum((x*rsqrt(deg_out))[src] -> dst) * rsqrt(deg_in)) @ W + b
// Reordering (linear): do @W first for layer 1; share aggregation for W2/W3.
// GEMMs run on matrix cores via fp16 hi/lo split-compensation (error ~2^-22,
// i.e. fp32-grade): C = Ah@Bh + Ah@Bl + Al@Bh with f32 accumulate.
// A operand is split fp32->hi/lo IN-REGISTER during LDS staging (no global
// fp16 copies of A; workspace stays ~25 MB, matching the proven footprint).

#define NN 10000
#define NE 320000
#define FD 512
#define H1 256
#define H2 128

typedef _Float16 half8 __attribute__((ext_vector_type(8)));
typedef _Float16 half4 __attribute__((ext_vector_type(4)));
typedef float f32x4 __attribute__((ext_vector_type(4)));

__device__ __forceinline__ void acc4(float4& a, const float4 v) {
    a.x += v.x; a.y += v.y; a.z += v.z; a.w += v.w;
}

__global__ void k_zero2(int* __restrict__ a, int* __restrict__ b, int n) {
    int i = blockIdx.x * blockDim.x + threadIdx.x;
    if (i < n) { a[i] = 0; b[i] = 0; }
}

__global__ void k_count(const int* __restrict__ src, const int* __restrict__ dst,
                        int* __restrict__ co, int* __restrict__ ci) {
    int e = blockIdx.x * blockDim.x + threadIdx.x;
    if (e < NE) {
        atomicAdd(&co[src[e]], 1);
        atomicAdd(&ci[dst[e]], 1);
    }
}

// One block: exclusive scan of in-degrees -> row_ptr; rsqrt of clamped degrees; zero cursors.
__global__ __launch_bounds__(1024) void k_scan(const int* __restrict__ ci, const int* __restrict__ co,
                                               int* __restrict__ row_ptr, int* __restrict__ cursor,
                                               float* __restrict__ rs_in, float* __restrict__ rs_out) {
    __shared__ int sm[1024];
    int tid = threadIdx.x;
    const int CH = (NN + 1023) / 1024;  // 10
    int base = tid * CH;
    int local[CH];
    int s = 0;
    #pragma unroll
    for (int i = 0; i < CH; ++i) {
        int idx = base + i;
        local[i] = s;
        if (idx < NN) s += ci[idx];
    }
    sm[tid] = s;
    __syncthreads();
    for (int off = 1; off < 1024; off <<= 1) {
        int v = (tid >= off) ? sm[tid - off] : 0;
        __syncthreads();
        sm[tid] += v;
        __syncthreads();
    }
    int excl = sm[tid] - s;
    #pragma unroll
    for (int i = 0; i < CH; ++i) {
        int idx = base + i;
        if (idx < NN) row_ptr[idx] = excl + local[i];
    }
    if (tid == 1023) row_ptr[NN] = sm[1023];
    for (int i = tid; i < NN; i += 1024) {
        int a = ci[i], b = co[i];
        rs_in[i]  = rsqrtf((float)(a > 1 ? a : 1));
        rs_out[i] = rsqrtf((float)(b > 1 ? b : 1));
        cursor[i] = 0;
    }
}

__global__ void k_bucket(const int* __restrict__ src, const int* __restrict__ dst,
                         const int* __restrict__ row_ptr, int* __restrict__ cursor,
                         int* __restrict__ esrc) {
    int e = blockIdx.x * blockDim.x + threadIdx.x;
    if (e < NE) {
        int d = dst[e];
        int p = row_ptr[d] + atomicAdd(&cursor[d], 1);
        esrc[p] = src[e];
    }
}

// W1[512][256] -> W1T[256][512] hi/lo; [W2|W3][256][128]x2 -> WcT[256][256] hi/lo; biasC=[b2|b3]
__global__ void k_castW(const float* __restrict__ W1, const float* __restrict__ W2,
                        const float* __restrict__ W3, const float* __restrict__ b2,
                        const float* __restrict__ b3,
                        _Float16* __restrict__ W1Th, _Float16* __restrict__ W1Tl,
                        _Float16* __restrict__ WcTh, _Float16* __restrict__ WcTl,
                        float* __restrict__ biasC) {
    int idx = blockIdx.x * blockDim.x + threadIdx.x;
    if (idx < FD * H1) {
        int k = idx >> 8, n = idx & 255;     // coalesced read over n
        float v = W1[idx];
        _Float16 h = (_Float16)v;
        W1Th[n * FD + k] = h;
        W1Tl[n * FD + k] = (_Float16)(v - (float)h);
    } else if (idx < FD * H1 + H1 * H1) {
        int j = idx - FD * H1;
        int k = j >> 8, n = j & 255;
        float v = (n < H2) ? W2[k * H2 + n] : W3[k * H2 + (n - H2)];
        _Float16 h = (_Float16)v;
        WcTh[n * H1 + k] = h;
        WcTl[n * H1 + k] = (_Float16)(v - (float)h);
        if (k == 0) biasC[n] = (n < H2) ? b2[n] : b3[n - H2];
    }
}

// C[M][256] f32 = (diag(ascale?) * A) @ BT^T (+bias).
// A=[M][K] fp32 (split hi/lo in-register at staging), BT=[256][K] fp16 hi/lo.
// BM=BN=64, BK=64, 256 threads = 4 waves 2x2, each wave 32x32 via 2x2 16x16x32 frags.
// 3-term compensation: AhBh + AhBl + AlBh.
template <int K>
__global__ __launch_bounds__(256) void k_gemm16(
    const float* __restrict__ A, const float* __restrict__ ascale,
    const _Float16* __restrict__ BTh, const _Float16* __restrict__ BTl,
    const float* __restrict__ bias, float* __restrict__ C, int M) {
    __shared__ __align__(16) _Float16 Ahs[64][72];  // 144B row stride: 16B-mult, bank-friendly
    __shared__ __align__(16) _Float16 Als[64][72];
    __shared__ __align__(16) _Float16 Bhs[64][72];
    __shared__ __align__(16) _Float16 Bls[64][72];
    int tid = threadIdx.x;
    int lane = tid & 63;
    int w = tid >> 6;
    int wr = (w >> 1) * 32, wc = (w & 1) * 32;
    int bm = blockIdx.x * 64, bn = blockIdx.y * 64;
    f32x4 acc[2][2] = {};
    for (int k0 = 0; k0 < K; k0 += 64) {
        __syncthreads();
        // A: 64 rows x 16 float4 chunks = 1024, 4 iters; convert fp32 -> hi/lo
        #pragma unroll
        for (int i = 0; i < 4; ++i) {
            int lin = i * 256 + tid;
            int r = lin >> 4, c = lin & 15;
            int gr = bm + r;
            float4 v = {0.f, 0.f, 0.f, 0.f};
            float s = 1.0f;
            if (gr < M) {
                v = *(const float4*)(A + (size_t)gr * K + k0 + c * 4);
                if (ascale) s = ascale[gr];
            }
            v.x *= s; v.y *= s; v.z *= s; v.w *= s;
            half4 hh = { (_Float16)v.x, (_Float16)v.y, (_Float16)v.z, (_Float16)v.w };
            half4 ll = { (_Float16)(v.x - (float)hh.x), (_Float16)(v.y - (float)hh.y),
                         (_Float16)(v.z - (float)hh.z), (_Float16)(v.w - (float)hh.w) };
            *(half4*)&Ahs[r][c * 4] = hh;
            *(half4*)&Als[r][c * 4] = ll;
        }
        // B: 64 rows x 8 int4 chunks = 512 per matrix, 2 iters each (pre-split fp16)
        #pragma unroll
        for (int i = 0; i < 2; ++i) {
            int lin = i * 256 + tid;
            int r = lin >> 3, c = lin & 7;
            *(int4*)&Bhs[r][c * 8] = *(const int4*)(BTh + (size_t)(bn + r) * K + k0 + c * 8);
            *(int4*)&Bls[r][c * 8] = *(const int4*)(BTl + (size_t)(bn + r) * K + k0 + c * 8);
        }
        __syncthreads();
        #pragma unroll
        for (int ks = 0; ks < 2; ++ks) {
            int kof = ks * 32 + ((lane >> 4) << 3);
            half8 ah[2], al[2], bh[2], bl[2];
            #pragma unroll
            for (int f = 0; f < 2; ++f) {
                ah[f] = *(const half8*)&Ahs[wr + f * 16 + (lane & 15)][kof];
                al[f] = *(const half8*)&Als[wr + f * 16 + (lane & 15)][kof];
                bh[f] = *(const half8*)&Bhs[wc + f * 16 + (lane & 15)][kof];
                bl[f] = *(const half8*)&Bls[wc + f * 16 + (lane & 15)][kof];
            }
            #pragma unroll
            for (int i = 0; i < 2; ++i)
                #pragma unroll
                for (int j = 0; j < 2; ++j) {
                    acc[i][j] = __builtin_amdgcn_mfma_f32_16x16x32_f16(ah[i], bh[j], acc[i][j], 0, 0, 0);
                    acc[i][j] = __builtin_amdgcn_mfma_f32_16x16x32_f16(ah[i], bl[j], acc[i][j], 0, 0, 0);
                    acc[i][j] = __builtin_amdgcn_mfma_f32_16x16x32_f16(al[i], bh[j], acc[i][j], 0, 0, 0);
                }
        }
    }
    int quad = lane >> 4, c16 = lane & 15;
    #pragma unroll
    for (int i = 0; i < 2; ++i) {
        int row0 = bm + wr + i * 16 + quad * 4;
        #pragma unroll
        for (int j = 0; j < 2; ++j) {
            int col = bn + wc + j * 16 + c16;
            float bb = bias ? bias[col] : 0.0f;
            #pragma unroll
            for (int r = 0; r < 4; ++r) {
                int row = row0 + r;
                if (row < M) C[(size_t)row * H1 + col] = acc[i][j][r] + bb;
            }
        }
    }
}

// One wave per node: sum rows in[esrc[e]][0..255], scale, (opt) +bias,relu,*rs_out.
template <bool FIRST>
__global__ __launch_bounds__(256) void k_agg(const float* __restrict__ in, float* __restrict__ out,
                                             const int* __restrict__ esrc, const int* __restrict__ row_ptr,
                                             const float* __restrict__ rs_in, const float* __restrict__ rs_out,
                                             const float* __restrict__ bias) {
    int node = (blockIdx.x * blockDim.x + threadIdx.x) >> 6;
    int lane = threadIdx.x & 63;
    if (node >= NN) return;
    int beg = row_ptr[node], end = row_ptr[node + 1];
    float4 acc = {0.f, 0.f, 0.f, 0.f};
    int e = beg;
    for (; e + 4 <= end; e += 4) {
        int s0 = esrc[e + 0], s1 = esrc[e + 1], s2 = esrc[e + 2], s3 = esrc[e + 3];
        float4 v0 = ((const float4*)(in + (size_t)s0 * H1))[lane];
        float4 v1 = ((const float4*)(in + (size_t)s1 * H1))[lane];
        float4 v2 = ((const float4*)(in + (size_t)s2 * H1))[lane];
        float4 v3 = ((const float4*)(in + (size_t)s3 * H1))[lane];
        acc4(acc, v0); acc4(acc, v1); acc4(acc, v2); acc4(acc, v3);
    }
    for (; e < end; ++e) {
        float4 v0 = ((const float4*)(in + (size_t)esrc[e] * H1))[lane];
        acc4(acc, v0);
    }
    float si = rs_in[node];
    float4 r;
    r.x = acc.x * si; r.y = acc.y * si; r.z = acc.z * si; r.w = acc.w * si;
    if (FIRST) {
        float4 bb = ((const float4*)bias)[lane];
        float so = rs_out[node];
        r.x = fmaxf(r.x + bb.x, 0.f) * so;
        r.y = fmaxf(r.y + bb.y, 0.f) * so;
        r.z = fmaxf(r.z + bb.z, 0.f) * so;
        r.w = fmaxf(r.w + bb.w, 0.f) * so;
    }
    ((float4*)(out + (size_t)node * H1))[lane] = r;
}

// z = mean + noise*exp(log_std), cast fp16 (fp16 not bf16: 2^-11 rounding keeps
// worst-case sigmoid error ~0.007 << 0.02 threshold)
__global__ void k_z(const float* __restrict__ ml, const float* __restrict__ noise,
                    _Float16* __restrict__ z) {
    int i = blockIdx.x * blockDim.x + threadIdx.x;
    if (i < NN * H2) {
        int r = i >> 7, c = i & 127;
        float mean = ml[(size_t)r * 256 + c];
        float ls   = ml[(size_t)r * 256 + 128 + c];
        z[i] = (_Float16)(mean + noise[i] * __expf(ls));
    }
}

// out = sigmoid(Z @ Z^T). 128x128 tile/block (4 waves, 64x64 each), K=128 staged 2x64 in LDS.
// mfma_f32_16x16x32_f16: A[m=lane&15][k=quad*8+j]; C: col=lane&15, row=quad*4+reg.
__global__ __launch_bounds__(256) void k_decoder(const _Float16* __restrict__ Z, float* __restrict__ out) {
    __shared__ __align__(16) _Float16 As[128][72];  // stride 72 halves = 144 B (16B-mult, bank-safe)
    __shared__ __align__(16) _Float16 Bs[128][72];
    int tid = threadIdx.x;
    int lane = tid & 63;
    int w = tid >> 6;
    int wrow = (w >> 1) * 64;
    int wcol = (w & 1) * 64;
    int rowBase = blockIdx.y * 128;
    int colBase = blockIdx.x * 128;
    f32x4 acc[4][4] = {};
    for (int s = 0; s < 2; ++s) {
        __syncthreads();
        #pragma unroll
        for (int i = 0; i < 4; ++i) {
            int lin = i * 256 + tid;       // 0..1023 chunk id
            int r = lin >> 3, c = lin & 7; // 8 chunks of 8 halves per row
            int4 v = {0, 0, 0, 0};
            int gr = rowBase + r;
            if (gr < NN) v = *(const int4*)(Z + (size_t)gr * H2 + s * 64 + c * 8);
            *(int4*)&As[r][c * 8] = v;
            int4 u = {0, 0, 0, 0};
            int gc = colBase + r;
            if (gc < NN) u = *(const int4*)(Z + (size_t)gc * H2 + s * 64 + c * 8);
            *(int4*)&Bs[r][c * 8] = u;
        }
        __syncthreads();
        #pragma unroll
        for (int kk = 0; kk < 2; ++kk) {
            int kof = kk * 32 + ((lane >> 4) << 3);
            half8 a[4], b[4];
            #pragma unroll
            for (int f = 0; f < 4; ++f) a[f] = *(const half8*)&As[wrow + f * 16 + (lane & 15)][kof];
            #pragma unroll
            for (int f = 0; f < 4; ++f) b[f] = *(const half8*)&Bs[wcol + f * 16 + (lane & 15)][kof];
            #pragma unroll
            for (int i = 0; i < 4; ++i)
                #pragma unroll
                for (int j = 0; j < 4; ++j)
                    acc[i][j] = __builtin_amdgcn_mfma_f32_16x16x32_f16(a[i], b[j], acc[i][j], 0, 0, 0);
        }
    }
    #pragma unroll
    for (int i = 0; i < 4; ++i) {
        int row0 = rowBase + wrow + i * 16 + ((lane >> 4) << 2);
        #pragma unroll
        for (int j = 0; j < 4; ++j) {
            int col = colBase + wcol + j * 16 + (lane & 15);
            if (col < NN) {
                #pragma unroll
                for (int r = 0; r < 4; ++r) {
                    int row = row0 + r;
                    if (row < NN) {
                        float x = acc[i][j][r];
                        float sg = 1.0f / (1.0f + __expf(-x));
                        __builtin_nontemporal_store(sg, out + (size_t)row * NN + col);
                    }
                }
            }
        }
    }
}

extern "C" void kernel_launch(void* const* d_in, const int* in_sizes, int n_in,
                              void* d_out, int out_size, void* d_ws, size_t ws_size,
                              hipStream_t stream) {
    const float* features = (const float*)d_in[0];
    const int*   src      = (const int*)d_in[1];
    const int*   dst      = (const int*)d_in[2];
    const float* noise    = (const float*)d_in[3];
    const float* W1 = (const float*)d_in[4];
    const float* b1 = (const float*)d_in[5];
    const float* W2 = (const float*)d_in[6];
    const float* b2 = (const float*)d_in[7];
    const float* W3 = (const float*)d_in[8];
    const float* b3 = (const float*)d_in[9];
    float* out = (float*)d_out;
    (void)in_sizes; (void)n_in; (void)out_size; (void)ws_size;

    char* ws = (char*)d_ws;
    size_t off = 0;
    auto alloc = [&](size_t bytes) -> void* {
        void* p = ws + off;
        off += (bytes + 255) & ~(size_t)255;
        return p;
    };
    int* degc_out = (int*)alloc(NN * sizeof(int));
    int* degc_in  = (int*)alloc(NN * sizeof(int));
    int* row_ptr  = (int*)alloc((NN + 1) * sizeof(int));
    int* cursor   = (int*)alloc(NN * sizeof(int));
    int* esrc     = (int*)alloc(NE * sizeof(int));
    float* rs_out = (float*)alloc(NN * sizeof(float));
    float* rs_in  = (float*)alloc(NN * sizeof(float));
    _Float16* W1Th = (_Float16*)alloc((size_t)H1 * FD * sizeof(_Float16));
    _Float16* W1Tl = (_Float16*)alloc((size_t)H1 * FD * sizeof(_Float16));
    _Float16* WcTh = (_Float16*)alloc((size_t)H1 * H1 * sizeof(_Float16));
    _Float16* WcTl = (_Float16*)alloc((size_t)H1 * H1 * sizeof(_Float16));
    float* biasC  = (float*)alloc(H1 * sizeof(float));
    float* bufA   = (float*)alloc((size_t)NN * H1 * sizeof(float));   // y1, then agg2
    float* bufB   = (float*)alloc((size_t)NN * H1 * sizeof(float));   // h_scaled, then mean|log_std
    _Float16* Zh  = (_Float16*)alloc((size_t)NN * H2 * sizeof(_Float16));

    k_zero2<<<(NN + 255) / 256, 256, 0, stream>>>(degc_out, degc_in, NN);
    k_count<<<(NE + 255) / 256, 256, 0, stream>>>(src, dst, degc_out, degc_in);
    k_scan<<<1, 1024, 0, stream>>>(degc_in, degc_out, row_ptr, cursor, rs_in, rs_out);
    k_bucket<<<(NE + 255) / 256, 256, 0, stream>>>(src, dst, row_ptr, cursor, esrc);
    k_castW<<<(FD * H1 + H1 * H1 + 255) / 256, 256, 0, stream>>>(
        W1, W2, W3, b2, b3, W1Th, W1Tl, WcTh, WcTl, biasC);

    // y1 = (features * rs_out) @ W1   (MFMA, split-compensated, in-staging convert)
    k_gemm16<FD><<<dim3((NN + 63) / 64, H1 / 64), 256, 0, stream>>>(
        features, rs_out, W1Th, W1Tl, nullptr, bufA, NN);
    // h_scaled = relu(agg(y1)*rs_in + b1) * rs_out
    k_agg<true><<<NN / 4, 256, 0, stream>>>(bufA, bufB, esrc, row_ptr, rs_in, rs_out, b1);
    // agg2 = agg(h_scaled) * rs_in
    k_agg<false><<<NN / 4, 256, 0, stream>>>(bufB, bufA, esrc, row_ptr, rs_in, nullptr, nullptr);
    // [mean | log_std] = agg2 @ [W2|W3] + [b2|b3]   (MFMA, split-compensated)
    k_gemm16<H1><<<dim3((NN + 63) / 64, H1 / 64), 256, 0, stream>>>(
        bufA, nullptr, WcTh, WcTl, biasC, bufB, NN);
    k_z<<<(NN * H2 + 255) / 256, 256, 0, stream>>>(bufB, noise, Zh);
    k_decoder<<<dim3((NN + 127) / 128, (NN + 127) / 128), 256, 0, stream>>>(Zh, out);
}

// Round 3
// 625.602 us; speedup vs baseline: 1.0965x; 1.0561x over previous
//
#include <hip/hip_runtime.h>
#include <hip/hip_fp16.h>

// VGAE: h = relu(GC(x,W1)); agg2 = norm-agg(h); mean=agg2@W2+b2; ls=agg2@W3+b3;
// z = mean + noise*exp(ls); out = sigmoid(z @ z^T)
// GC(x,W) = (segsum((x*rsqrt(deg_out))[src] -> dst) * rsqrt(deg_in)) @ W + b
// Reordering (linear): do @W first for layer 1; share aggregation for W2/W3.
// GEMMs on matrix cores via fp16 hi/lo split-compensation (err ~2^-22, fp32-grade).
// Gather operands (y1, h) stored fp16: halves agg traffic; error ~1e-4 in z.
// GEMM2 fused with reparameterization (writes Zh fp16 directly).

#define NN 10000
#define NE 320000
#define FD 512
#define H1 256
#define H2 128

typedef _Float16 half8 __attribute__((ext_vector_type(8)));
typedef _Float16 half4 __attribute__((ext_vector_type(4)));
typedef float f32x4 __attribute__((ext_vector_type(4)));

__global__ void k_zero3(int* __restrict__ a, int* __restrict__ b, int* __restrict__ c, int n) {
    int i = blockIdx.x * blockDim.x + threadIdx.x;
    if (i < n) { a[i] = 0; b[i] = 0; c[i] = 0; }
}

__global__ void k_count(const int* __restrict__ src, const int* __restrict__ dst,
                        int* __restrict__ co, int* __restrict__ ci) {
    int e = blockIdx.x * blockDim.x + threadIdx.x;
    if (e < NE) {
        atomicAdd(&co[src[e]], 1);
        atomicAdd(&ci[dst[e]], 1);
    }
}

// One block: exclusive scan of in-degrees -> row_ptr; rsqrt of clamped degrees.
__global__ __launch_bounds__(1024) void k_scan(const int* __restrict__ ci, const int* __restrict__ co,
                                               int* __restrict__ row_ptr,
                                               float* __restrict__ rs_in, float* __restrict__ rs_out) {
    __shared__ int sm[1024];
    int tid = threadIdx.x;
    const int CH = (NN + 1023) / 1024;  // 10
    int base = tid * CH;
    int local[CH];
    int s = 0;
    #pragma unroll
    for (int i = 0; i < CH; ++i) {
        int idx = base + i;
        local[i] = s;
        if (idx < NN) s += ci[idx];
    }
    sm[tid] = s;
    __syncthreads();
    for (int off = 1; off < 1024; off <<= 1) {
        int v = (tid >= off) ? sm[tid - off] : 0;
        __syncthreads();
        sm[tid] += v;
        __syncthreads();
    }
    int excl = sm[tid] - s;
    #pragma unroll
    for (int i = 0; i < CH; ++i) {
        int idx = base + i;
        if (idx < NN) row_ptr[idx] = excl + local[i];
    }
    if (tid == 1023) row_ptr[NN] = sm[1023];
    for (int i = tid; i < NN; i += 1024) {
        int a = ci[i], b = co[i];
        rs_in[i]  = rsqrtf((float)(a > 1 ? a : 1));
        rs_out[i] = rsqrtf((float)(b > 1 ? b : 1));
    }
}

__global__ void k_bucket(const int* __restrict__ src, const int* __restrict__ dst,
                         const int* __restrict__ row_ptr, int* __restrict__ cursor,
                         int* __restrict__ esrc) {
    int e = blockIdx.x * blockDim.x + threadIdx.x;
    if (e < NE) {
        int d = dst[e];
        int p = row_ptr[d] + atomicAdd(&cursor[d], 1);
        esrc[p] = src[e];
    }
}

// W1[512][256] -> W1T[256][512] hi/lo; [W2|W3][256][128]x2 -> WcT[256][256] hi/lo.
__global__ void k_castW(const float* __restrict__ W1, const float* __restrict__ W2,
                        const float* __restrict__ W3,
                        _Float16* __restrict__ W1Th, _Float16* __restrict__ W1Tl,
                        _Float16* __restrict__ WcTh, _Float16* __restrict__ WcTl) {
    int idx = blockIdx.x * blockDim.x + threadIdx.x;
    if (idx < FD * H1) {
        int k = idx >> 8, n = idx & 255;     // coalesced read over n
        float v = W1[idx];
        _Float16 h = (_Float16)v;
        W1Th[n * FD + k] = h;
        W1Tl[n * FD + k] = (_Float16)(v - (float)h);
    } else if (idx < FD * H1 + H1 * H1) {
        int j = idx - FD * H1;
        int k = j >> 8, n = j & 255;
        float v = (n < H2) ? W2[k * H2 + n] : W3[k * H2 + (n - H2)];
        _Float16 h = (_Float16)v;
        WcTh[n * H1 + k] = h;
        WcTl[n * H1 + k] = (_Float16)(v - (float)h);
    }
}

// y1[M][256] fp16 = (diag(rs_out) * features) @ W1T^T.  A fp32 split hi/lo in-register.
// BM=BN=64, BK=64, 256 threads = 4 waves 2x2, wave 32x32 via 2x2 16x16x32 frags.
// 3-term compensation: AhBh + AhBl + AlBh.
__global__ __launch_bounds__(256) void k_gemm1(
    const float* __restrict__ A, const float* __restrict__ ascale,
    const _Float16* __restrict__ BTh, const _Float16* __restrict__ BTl,
    _Float16* __restrict__ C, int M) {
    const int K = FD;
    __shared__ __align__(16) _Float16 Ahs[64][72];
    __shared__ __align__(16) _Float16 Als[64][72];
    __shared__ __align__(16) _Float16 Bhs[64][72];
    __shared__ __align__(16) _Float16 Bls[64][72];
    int tid = threadIdx.x;
    int lane = tid & 63;
    int w = tid >> 6;
    int wr = (w >> 1) * 32, wc = (w & 1) * 32;
    int bm = blockIdx.x * 64, bn = blockIdx.y * 64;
    f32x4 acc[2][2] = {};
    for (int k0 = 0; k0 < K; k0 += 64) {
        __syncthreads();
        #pragma unroll
        for (int i = 0; i < 4; ++i) {
            int lin = i * 256 + tid;
            int r = lin >> 4, c = lin & 15;
            int gr = bm + r;
            float4 v = {0.f, 0.f, 0.f, 0.f};
            float s = 1.0f;
            if (gr < M) {
                v = *(const float4*)(A + (size_t)gr * K + k0 + c * 4);
                s = ascale[gr];
            }
            v.x *= s; v.y *= s; v.z *= s; v.w *= s;
            half4 hh = { (_Float16)v.x, (_Float16)v.y, (_Float16)v.z, (_Float16)v.w };
            half4 ll = { (_Float16)(v.x - (float)hh[0]), (_Float16)(v.y - (float)hh[1]),
                         (_Float16)(v.z - (float)hh[2]), (_Float16)(v.w - (float)hh[3]) };
            *(half4*)&Ahs[r][c * 4] = hh;
            *(half4*)&Als[r][c * 4] = ll;
        }
        #pragma unroll
        for (int i = 0; i < 2; ++i) {
            int lin = i * 256 + tid;
            int r = lin >> 3, c = lin & 7;
            *(int4*)&Bhs[r][c * 8] = *(const int4*)(BTh + (size_t)(bn + r) * K + k0 + c * 8);
            *(int4*)&Bls[r][c * 8] = *(const int4*)(BTl + (size_t)(bn + r) * K + k0 + c * 8);
        }
        __syncthreads();
        #pragma unroll
        for (int ks = 0; ks < 2; ++ks) {
            int kof = ks * 32 + ((lane >> 4) << 3);
            half8 ah[2], al[2], bh[2], bl[2];
            #pragma unroll
            for (int f = 0; f < 2; ++f) {
                ah[f] = *(const half8*)&Ahs[wr + f * 16 + (lane & 15)][kof];
                al[f] = *(const half8*)&Als[wr + f * 16 + (lane & 15)][kof];
                bh[f] = *(const half8*)&Bhs[wc + f * 16 + (lane & 15)][kof];
                bl[f] = *(const half8*)&Bls[wc + f * 16 + (lane & 15)][kof];
            }
            #pragma unroll
            for (int i = 0; i < 2; ++i)
                #pragma unroll
                for (int j = 0; j < 2; ++j) {
                    acc[i][j] = __builtin_amdgcn_mfma_f32_16x16x32_f16(ah[i], bh[j], acc[i][j], 0, 0, 0);
                    acc[i][j] = __builtin_amdgcn_mfma_f32_16x16x32_f16(ah[i], bl[j], acc[i][j], 0, 0, 0);
                    acc[i][j] = __builtin_amdgcn_mfma_f32_16x16x32_f16(al[i], bh[j], acc[i][j], 0, 0, 0);
                }
        }
    }
    int quad = lane >> 4, c16 = lane & 15;
    #pragma unroll
    for (int i = 0; i < 2; ++i) {
        int row0 = bm + wr + i * 16 + quad * 4;
        #pragma unroll
        for (int j = 0; j < 2; ++j) {
            int col = bn + wc + j * 16 + c16;
            #pragma unroll
            for (int r = 0; r < 4; ++r) {
                int row = row0 + r;
                if (row < M) C[(size_t)row * H1 + col] = (_Float16)acc[i][j][r];
            }
        }
    }
}

// [mean|ls] = agg2 @ [W2|W3] + [b2|b3]; z = mean + noise*exp(ls) -> Zh fp16.
// Block: 64 rows x 64 cols of H2; dual accumulators (mean from WcT rows c, ls from rows c+128).
__global__ __launch_bounds__(256) void k_gemm2z(
    const float* __restrict__ A,
    const _Float16* __restrict__ BTh, const _Float16* __restrict__ BTl,
    const float* __restrict__ b2, const float* __restrict__ b3,
    const float* __restrict__ noise, _Float16* __restrict__ Zh, int M) {
    const int K = H1;
    __shared__ __align__(16) _Float16 Ahs[64][72];
    __shared__ __align__(16) _Float16 Als[64][72];
    __shared__ __align__(16) _Float16 Bmh[64][72];
    __shared__ __align__(16) _Float16 Bml[64][72];
    __shared__ __align__(16) _Float16 Blh[64][72];
    __shared__ __align__(16) _Float16 Bll[64][72];
    int tid = threadIdx.x;
    int lane = tid & 63;
    int w = tid >> 6;
    int wr = (w >> 1) * 32, wc = (w & 1) * 32;
    int bm = blockIdx.x * 64;
    int c0 = blockIdx.y * 64;      // output column block within H2=128
    f32x4 accm[2][2] = {};
    f32x4 accl[2][2] = {};
    for (int k0 = 0; k0 < K; k0 += 64) {
        __syncthreads();
        #pragma unroll
        for (int i = 0; i < 4; ++i) {
            int lin = i * 256 + tid;
            int r = lin >> 4, c = lin & 15;
            int gr = bm + r;
            float4 v = {0.f, 0.f, 0.f, 0.f};
            if (gr < M) v = *(const float4*)(A + (size_t)gr * K + k0 + c * 4);
            half4 hh = { (_Float16)v.x, (_Float16)v.y, (_Float16)v.z, (_Float16)v.w };
            half4 ll = { (_Float16)(v.x - (float)hh[0]), (_Float16)(v.y - (float)hh[1]),
                         (_Float16)(v.z - (float)hh[2]), (_Float16)(v.w - (float)hh[3]) };
            *(half4*)&Ahs[r][c * 4] = hh;
            *(half4*)&Als[r][c * 4] = ll;
        }
        #pragma unroll
        for (int i = 0; i < 2; ++i) {
            int lin = i * 256 + tid;
            int r = lin >> 3, c = lin & 7;
            size_t rm = (size_t)(c0 + r) * K + k0 + c * 8;        // mean: WcT row c0+r
            size_t rl = (size_t)(128 + c0 + r) * K + k0 + c * 8;  // ls:   WcT row 128+c0+r
            *(int4*)&Bmh[r][c * 8] = *(const int4*)(BTh + rm);
            *(int4*)&Bml[r][c * 8] = *(const int4*)(BTl + rm);
            *(int4*)&Blh[r][c * 8] = *(const int4*)(BTh + rl);
            *(int4*)&Bll[r][c * 8] = *(const int4*)(BTl + rl);
        }
        __syncthreads();
        #pragma unroll
        for (int ks = 0; ks < 2; ++ks) {
            int kof = ks * 32 + ((lane >> 4) << 3);
            half8 ah[2], al[2], mh[2], ml[2], lh[2], ll[2];
            #pragma unroll
            for (int f = 0; f < 2; ++f) {
                ah[f] = *(const half8*)&Ahs[wr + f * 16 + (lane & 15)][kof];
                al[f] = *(const half8*)&Als[wr + f * 16 + (lane & 15)][kof];
                mh[f] = *(const half8*)&Bmh[wc + f * 16 + (lane & 15)][kof];
                ml[f] = *(const half8*)&Bml[wc + f * 16 + (lane & 15)][kof];
                lh[f] = *(const half8*)&Blh[wc + f * 16 + (lane & 15)][kof];
                ll[f] = *(const half8*)&Bll[wc + f * 16 + (lane & 15)][kof];
            }
            #pragma unroll
            for (int i = 0; i < 2; ++i)
                #pragma unroll
                for (int j = 0; j < 2; ++j) {
                    accm[i][j] = __builtin_amdgcn_mfma_f32_16x16x32_f16(ah[i], mh[j], accm[i][j], 0, 0, 0);
                    accm[i][j] = __builtin_amdgcn_mfma_f32_16x16x32_f16(ah[i], ml[j], accm[i][j], 0, 0, 0);
                    accm[i][j] = __builtin_amdgcn_mfma_f32_16x16x32_f16(al[i], mh[j], accm[i][j], 0, 0, 0);
                    accl[i][j] = __builtin_amdgcn_mfma_f32_16x16x32_f16(ah[i], lh[j], accl[i][j], 0, 0, 0);
                    accl[i][j] = __builtin_amdgcn_mfma_f32_16x16x32_f16(ah[i], ll[j], accl[i][j], 0, 0, 0);
                    accl[i][j] = __builtin_amdgcn_mfma_f32_16x16x32_f16(al[i], lh[j], accl[i][j], 0, 0, 0);
                }
        }
    }
    int quad = lane >> 4, c16 = lane & 15;
    #pragma unroll
    for (int i = 0; i < 2; ++i) {
        int row0 = bm + wr + i * 16 + quad * 4;
        #pragma unroll
        for (int j = 0; j < 2; ++j) {
            int c = c0 + wc + j * 16 + c16;   // 0..127
            float bm_ = b2[c], bl_ = b3[c];
            #pragma unroll
            for (int r = 0; r < 4; ++r) {
                int row = row0 + r;
                if (row < M) {
                    float mean = accm[i][j][r] + bm_;
                    float lsv  = accl[i][j][r] + bl_;
                    float z = mean + noise[(size_t)row * H2 + c] * __expf(lsv);
                    Zh[(size_t)row * H2 + c] = (_Float16)z;
                }
            }
        }
    }
}

// One wave per node: sum fp16 rows in[esrc[e]][0..255] in fp32, scale.
// FIRST: +bias, relu, *rs_out -> fp16. else: -> fp32 (feeds gemm2z staging split).
template <bool FIRST>
__global__ __launch_bounds__(256) void k_agg(const _Float16* __restrict__ in,
                                             _Float16* __restrict__ outh, float* __restrict__ outf,
                                             const int* __restrict__ esrc, const int* __restrict__ row_ptr,
                                             const float* __restrict__ rs_in, const float* __restrict__ rs_out,
                                             const float* __restrict__ bias) {
    int node = (blockIdx.x * blockDim.x + threadIdx.x) >> 6;
    int lane = threadIdx.x & 63;
    if (node >= NN) return;
    int beg = row_ptr[node], end = row_ptr[node + 1];
    float a0 = 0.f, a1 = 0.f, a2 = 0.f, a3 = 0.f;
    int e = beg;
    for (; e + 4 <= end; e += 4) {
        int s0 = esrc[e + 0], s1 = esrc[e + 1], s2 = esrc[e + 2], s3 = esrc[e + 3];
        half4 v0 = ((const half4*)(in + (size_t)s0 * H1))[lane];
        half4 v1 = ((const half4*)(in + (size_t)s1 * H1))[lane];
        half4 v2 = ((const half4*)(in + (size_t)s2 * H1))[lane];
        half4 v3 = ((const half4*)(in + (size_t)s3 * H1))[lane];
        a0 += (float)v0[0] + (float)v1[0] + (float)v2[0] + (float)v3[0];
        a1 += (float)v0[1] + (float)v1[1] + (float)v2[1] + (float)v3[1];
        a2 += (float)v0[2] + (float)v1[2] + (float)v2[2] + (float)v3[2];
        a3 += (float)v0[3] + (float)v1[3] + (float)v2[3] + (float)v3[3];
    }
    for (; e < end; ++e) {
        half4 v0 = ((const half4*)(in + (size_t)esrc[e] * H1))[lane];
        a0 += (float)v0[0]; a1 += (float)v0[1]; a2 += (float)v0[2]; a3 += (float)v0[3];
    }
    float si = rs_in[node];
    a0 *= si; a1 *= si; a2 *= si; a3 *= si;
    if (FIRST) {
        float4 bb = ((const float4*)bias)[lane];
        float so = rs_out[node];
        a0 = fmaxf(a0 + bb.x, 0.f) * so;
        a1 = fmaxf(a1 + bb.y, 0.f) * so;
        a2 = fmaxf(a2 + bb.z, 0.f) * so;
        a3 = fmaxf(a3 + bb.w, 0.f) * so;
        half4 hh = { (_Float16)a0, (_Float16)a1, (_Float16)a2, (_Float16)a3 };
        ((half4*)(outh + (size_t)node * H1))[lane] = hh;
    } else {
        float4 r = { a0, a1, a2, a3 };
        ((float4*)(outf + (size_t)node * H1))[lane] = r;
    }
}

// out = sigmoid(Z @ Z^T). 128x128 tile/block (4 waves, 64x64 each), K=128 staged 2x64 in LDS.
__global__ __launch_bounds__(256) void k_decoder(const _Float16* __restrict__ Z, float* __restrict__ out) {
    __shared__ __align__(16) _Float16 As[128][72];
    __shared__ __align__(16) _Float16 Bs[128][72];
    int tid = threadIdx.x;
    int lane = tid & 63;
    int w = tid >> 6;
    int wrow = (w >> 1) * 64;
    int wcol = (w & 1) * 64;
    int rowBase = blockIdx.y * 128;
    int colBase = blockIdx.x * 128;
    f32x4 acc[4][4] = {};
    for (int s = 0; s < 2; ++s) {
        __syncthreads();
        #pragma unroll
        for (int i = 0; i < 4; ++i) {
            int lin = i * 256 + tid;
            int r = lin >> 3, c = lin & 7;
            int4 v = {0, 0, 0, 0};
            int gr = rowBase + r;
            if (gr < NN) v = *(const int4*)(Z + (size_t)gr * H2 + s * 64 + c * 8);
            *(int4*)&As[r][c * 8] = v;
            int4 u = {0, 0, 0, 0};
            int gc = colBase + r;
            if (gc < NN) u = *(const int4*)(Z + (size_t)gc * H2 + s * 64 + c * 8);
            *(int4*)&Bs[r][c * 8] = u;
        }
        __syncthreads();
        #pragma unroll
        for (int kk = 0; kk < 2; ++kk) {
            int kof = kk * 32 + ((lane >> 4) << 3);
            half8 a[4], b[4];
            #pragma unroll
            for (int f = 0; f < 4; ++f) a[f] = *(const half8*)&As[wrow + f * 16 + (lane & 15)][kof];
            #pragma unroll
            for (int f = 0; f < 4; ++f) b[f] = *(const half8*)&Bs[wcol + f * 16 + (lane & 15)][kof];
            #pragma unroll
            for (int i = 0; i < 4; ++i)
                #pragma unroll
                for (int j = 0; j < 4; ++j)
                    acc[i][j] = __builtin_amdgcn_mfma_f32_16x16x32_f16(a[i], b[j], acc[i][j], 0, 0, 0);
        }
    }
    #pragma unroll
    for (int i = 0; i < 4; ++i) {
        int row0 = rowBase + wrow + i * 16 + ((lane >> 4) << 2);
        #pragma unroll
        for (int j = 0; j < 4; ++j) {
            int col = colBase + wcol + j * 16 + (lane & 15);
            if (col < NN) {
                #pragma unroll
                for (int r = 0; r < 4; ++r) {
                    int row = row0 + r;
                    if (row < NN) {
                        float x = acc[i][j][r];
                        float sg = __builtin_amdgcn_rcpf(1.0f + __expf(-x));  // v_rcp: saves IEEE div seq
                        __builtin_nontemporal_store(sg, out + (size_t)row * NN + col);
                    }
                }
            }
        }
    }
}

extern "C" void kernel_launch(void* const* d_in, const int* in_sizes, int n_in,
                              void* d_out, int out_size, void* d_ws, size_t ws_size,
                              hipStream_t stream) {
    const float* features = (const float*)d_in[0];
    const int*   src      = (const int*)d_in[1];
    const int*   dst      = (const int*)d_in[2];
    const float* noise    = (const float*)d_in[3];
    const float* W1 = (const float*)d_in[4];
    const float* b1 = (const float*)d_in[5];
    const float* W2 = (const float*)d_in[6];
    const float* b2 = (const float*)d_in[7];
    const float* W3 = (const float*)d_in[8];
    const float* b3 = (const float*)d_in[9];
    float* out = (float*)d_out;
    (void)in_sizes; (void)n_in; (void)out_size; (void)ws_size;

    char* ws = (char*)d_ws;
    size_t off = 0;
    auto alloc = [&](size_t bytes) -> void* {
        void* p = ws + off;
        off += (bytes + 255) & ~(size_t)255;
        return p;
    };
    int* degc_out = (int*)alloc(NN * sizeof(int));
    int* degc_in  = (int*)alloc(NN * sizeof(int));
    int* row_ptr  = (int*)alloc((NN + 1) * sizeof(int));
    int* cursor   = (int*)alloc(NN * sizeof(int));
    int* esrc     = (int*)alloc(NE * sizeof(int));
    float* rs_out = (float*)alloc(NN * sizeof(float));
    float* rs_in  = (float*)alloc(NN * sizeof(float));
    _Float16* W1Th = (_Float16*)alloc((size_t)H1 * FD * sizeof(_Float16));
    _Float16* W1Tl = (_Float16*)alloc((size_t)H1 * FD * sizeof(_Float16));
    _Float16* WcTh = (_Float16*)alloc((size_t)H1 * H1 * sizeof(_Float16));
    _Float16* WcTl = (_Float16*)alloc((size_t)H1 * H1 * sizeof(_Float16));
    _Float16* y1h  = (_Float16*)alloc((size_t)NN * H1 * sizeof(_Float16));
    _Float16* hh   = (_Float16*)alloc((size_t)NN * H1 * sizeof(_Float16));
    float* agg2    = (float*)alloc((size_t)NN * H1 * sizeof(float));
    _Float16* Zh   = (_Float16*)alloc((size_t)NN * H2 * sizeof(_Float16));

    k_zero3<<<(NN + 255) / 256, 256, 0, stream>>>(degc_out, degc_in, cursor, NN);
    k_count<<<(NE + 255) / 256, 256, 0, stream>>>(src, dst, degc_out, degc_in);
    k_scan<<<1, 1024, 0, stream>>>(degc_in, degc_out, row_ptr, rs_in, rs_out);
    k_bucket<<<(NE + 255) / 256, 256, 0, stream>>>(src, dst, row_ptr, cursor, esrc);
    k_castW<<<(FD * H1 + H1 * H1 + 255) / 256, 256, 0, stream>>>(
        W1, W2, W3, W1Th, W1Tl, WcTh, WcTl);

    // y1 = (features * rs_out) @ W1  -> fp16
    k_gemm1<<<dim3((NN + 63) / 64, H1 / 64), 256, 0, stream>>>(
        features, rs_out, W1Th, W1Tl, y1h, NN);
    // h = relu(agg(y1)*rs_in + b1) * rs_out -> fp16
    k_agg<true><<<NN / 4, 256, 0, stream>>>(y1h, hh, nullptr, esrc, row_ptr, rs_in, rs_out, b1);
    // agg2 = agg(h) * rs_in -> fp32
    k_agg<false><<<NN / 4, 256, 0, stream>>>(hh, nullptr, agg2, esrc, row_ptr, rs_in, nullptr, nullptr);
    // z = (agg2@W2+b2) + noise*exp(agg2@W3+b3) -> Zh fp16 (fused)
    k_gemm2z<<<dim3((NN + 63) / 64, H2 / 64), 256, 0, stream>>>(
        agg2, WcTh, WcTl, b2, b3, noise, Zh, NN);
    k_decoder<<<dim3((NN + 127) / 128, (NN + 127) / 128), 256, 0, stream>>>(Zh, out);
}